// Round 1
// baseline (697.533 us; speedup 1.0000x reference)
//
#include <hip/hip_runtime.h>
#include <stdint.h>

#define N_NODES 50000
#define N_EDGES 1200000
#define FAN 192       // 2*D + E_DIM
#define NOUT 128      // gate(64) | val(64)
#define ZS 200        // LDS row stride for Z tile (bf16 elems), padded
#define TILE_E 64
#define N_TILES (N_EDGES / TILE_E)   // 18750
#define BN_EPS 1e-5f

typedef __bf16 bf16x8 __attribute__((ext_vector_type(8)));
typedef float  f32x4  __attribute__((ext_vector_type(4)));

__device__ __forceinline__ unsigned short f2bf(float f) {
  unsigned int b = __float_as_uint(f);
  b += 0x7fff + ((b >> 16) & 1);          // RNE
  return (unsigned short)(b >> 16);
}

__device__ __forceinline__ float softplus_f(float x) {
  return fmaxf(x, 0.f) + log1pf(__expf(-fabsf(x)));
}

// ---------------- Kernel A: init / pack ----------------
__global__ void init_kernel(const float* __restrict__ x,
                            const float* __restrict__ Wf,
                            const float* __restrict__ Ws,
                            float* __restrict__ message,
                            unsigned short* __restrict__ x_bf,
                            unsigned short* __restrict__ B_pack,
                            float* __restrict__ stats) {
  const int T0 = 800000;            // zero message, uint4 granularity
  const int T1 = T0 + 800000;       // x f32 -> bf16, float4 granularity
  const int T2 = T1 + NOUT * FAN;   // pack B
  const int T3 = T2 + 128;          // zero stats
  for (int id = blockIdx.x * 256 + threadIdx.x; id < T3; id += gridDim.x * 256) {
    if (id < T0) {
      ((uint4*)message)[id] = make_uint4(0u, 0u, 0u, 0u);
    } else if (id < T1) {
      int i = id - T0;
      float4 v = ((const float4*)x)[i];
      unsigned int lo = (unsigned int)f2bf(v.x) | ((unsigned int)f2bf(v.y) << 16);
      unsigned int hi = (unsigned int)f2bf(v.z) | ((unsigned int)f2bf(v.w) << 16);
      ((uint2*)x_bf)[i] = make_uint2(lo, hi);
    } else if (id < T2) {
      int p = id - T1;
      int n = p / FAN, k = p - n * FAN;
      float v = (n < 64) ? Wf[n * FAN + k] : Ws[(n - 64) * FAN + k];
      B_pack[n * FAN + k] = f2bf(v);
    } else {
      stats[id - T2] = 0.f;
    }
  }
}

// ---------------- Kernel B: edge GEMM + activations + scatter ----------------
__global__ __launch_bounds__(256)
void edge_kernel(const float* __restrict__ edge_attr,
                 const int* __restrict__ edge_source,
                 const int* __restrict__ edge_target,
                 const unsigned short* __restrict__ x_bf,
                 const unsigned short* __restrict__ B_pack,
                 const float* __restrict__ bf_bias,
                 const float* __restrict__ bs_bias,
                 float* __restrict__ message) {
  __shared__ unsigned short Zt[TILE_E * ZS];
  __shared__ int lds_src[TILE_E];

  const int t  = threadIdx.x;
  const int w  = t >> 6;       // wave 0..3
  const int l  = t & 63;       // lane
  const int ln = l & 15;       // MFMA col/row-in-16
  const int lk = l >> 4;       // k-chunk 0..3

  // B fragments in registers: wave w owns gate cols [16w,16w+16) and val cols
  // [64+16w, 64+16w+16)  (2 n-tiles x 6 k-steps x 8 bf16 = 48 VGPRs)
  bf16x8 bfrag[2][6];
  #pragma unroll
  for (int g = 0; g < 2; ++g) {
    int n = (w + 4 * g) * 16 + ln;
    #pragma unroll
    for (int kk = 0; kk < 6; ++kk)
      bfrag[g][kk] = *(const bf16x8*)(B_pack + n * FAN + kk * 32 + lk * 8);
  }
  const float bfv = bf_bias[w * 16 + ln];
  const float bsv = bs_bias[w * 16 + ln];

  for (int tile = blockIdx.x; tile < N_TILES; tile += gridDim.x) {
    const int e0 = tile * TILE_E;
    if (t < TILE_E) lds_src[t] = edge_source[e0 + t];

    // stage x[src] | x[tgt] halves: 64 rows x 2 segs x 8 chunks of 16B
    #pragma unroll
    for (int it = 0; it < 4; ++it) {
      int c = t + it * 256;             // [0,1024)
      int row = c >> 4, sub = c & 15;
      int seg = sub >> 3, j = sub & 7;
      int node = seg ? edge_target[e0 + row] : edge_source[e0 + row];
      uint4 v = *(const uint4*)(x_bf + node * 64 + j * 8);
      *(uint4*)(&Zt[row * ZS + seg * 64 + j * 8]) = v;
    }
    // stage edge_attr (contiguous 16KB), convert f32->bf16
    #pragma unroll
    for (int it = 0; it < 4; ++it) {
      int c = t + it * 256;             // [0,1024)
      int row = c >> 4, q = c & 15;
      float4 v = *(const float4*)(edge_attr + (size_t)(e0 + row) * 64 + q * 4);
      unsigned int lo = (unsigned int)f2bf(v.x) | ((unsigned int)f2bf(v.y) << 16);
      unsigned int hi = (unsigned int)f2bf(v.z) | ((unsigned int)f2bf(v.w) << 16);
      *(uint2*)(&Zt[row * ZS + 128 + q * 4]) = make_uint2(lo, hi);
    }
    __syncthreads();

    // GEMM: [64 edges x 192] @ [192 x 128] ; wave w does all 4 m-tiles for its 2 n-tiles
    f32x4 acc[4][2] = {};
    #pragma unroll
    for (int kk = 0; kk < 6; ++kk) {
      #pragma unroll
      for (int i = 0; i < 4; ++i) {
        bf16x8 a = *(const bf16x8*)(&Zt[(i * 16 + ln) * ZS + kk * 32 + lk * 8]);
        acc[i][0] = __builtin_amdgcn_mfma_f32_16x16x32_bf16(a, bfrag[0][kk], acc[i][0], 0, 0, 0);
        acc[i][1] = __builtin_amdgcn_mfma_f32_16x16x32_bf16(a, bfrag[1][kk], acc[i][1], 0, 0, 0);
      }
    }

    // epilogue: activations + scatter  (C/D layout: col=ln, row=(lk*4+r))
    #pragma unroll
    for (int i = 0; i < 4; ++i) {
      #pragma unroll
      for (int r = 0; r < 4; ++r) {
        float gl = acc[i][0][r] + bfv;
        float vl = acc[i][1][r] + bsv;
        float gate = 1.f / (1.f + __expf(-gl));
        float val  = softplus_f(vl);
        int m = i * 16 + lk * 4 + r;
        atomicAdd(&message[(size_t)lds_src[m] * 64 + w * 16 + ln], gate * val);
      }
    }
    __syncthreads();   // Zt reuse by next tile
  }
}

// ---------------- Kernel C: BN stats (sum, sumsq per channel) ----------------
__global__ void stats_kernel(const float* __restrict__ msg,
                             float* __restrict__ stats) {
  __shared__ float red[256];
  int t = threadIdx.x;
  int c = t & 63, g = t >> 6;
  float s1 = 0.f, s2 = 0.f;
  for (int r = blockIdx.x * 4 + g; r < N_NODES; r += gridDim.x * 4) {
    float v = msg[(size_t)r * 64 + c];
    s1 += v; s2 += v * v;
  }
  red[t] = s1;
  __syncthreads();
  if (t < 64) atomicAdd(&stats[t], red[t] + red[t + 64] + red[t + 128] + red[t + 192]);
  __syncthreads();
  red[t] = s2;
  __syncthreads();
  if (t < 64) atomicAdd(&stats[64 + t], red[t] + red[t + 64] + red[t + 128] + red[t + 192]);
}

// ---------------- Kernel D: BN apply + residual softplus (in-place on out) ----------------
__global__ void final_kernel(const float* __restrict__ x,
                             const float* __restrict__ stats,
                             const float* __restrict__ gamma,
                             const float* __restrict__ beta,
                             float* __restrict__ out) {
  int idx = blockIdx.x * 256 + threadIdx.x;
  if (idx >= 800000) return;
  float4 mv = ((const float4*)out)[idx];
  float4 xv = ((const float4*)x)[idx];
  int c0 = (idx & 15) * 4;
  float m[4]  = {mv.x, mv.y, mv.z, mv.w};
  float xx[4] = {xv.x, xv.y, xv.z, xv.w};
  float r[4];
  #pragma unroll
  for (int j = 0; j < 4; ++j) {
    int c = c0 + j;
    float mean = stats[c] * (1.f / N_NODES);
    float var  = stats[64 + c] * (1.f / N_NODES) - mean * mean;
    float bn = (m[j] - mean) * rsqrtf(var + BN_EPS) * gamma[c] + beta[c];
    r[j] = softplus_f(xx[j] + bn);
  }
  ((float4*)out)[idx] = make_float4(r[0], r[1], r[2], r[3]);
}

extern "C" void kernel_launch(void* const* d_in, const int* in_sizes, int n_in,
                              void* d_out, int out_size, void* d_ws, size_t ws_size,
                              hipStream_t stream) {
  const float* x         = (const float*)d_in[0];
  const float* edge_attr = (const float*)d_in[1];
  const float* Wf        = (const float*)d_in[2];
  const float* bf        = (const float*)d_in[3];
  const float* Ws        = (const float*)d_in[4];
  const float* bs        = (const float*)d_in[5];
  const float* gamma     = (const float*)d_in[6];
  const float* beta      = (const float*)d_in[7];
  const int*   esrc      = (const int*)d_in[8];
  const int*   etgt      = (const int*)d_in[9];
  float* out = (float*)d_out;

  uint8_t* ws = (uint8_t*)d_ws;
  unsigned short* x_bf   = (unsigned short*)ws;                    // 6,400,000 B
  unsigned short* B_pack = (unsigned short*)(ws + 6400000);        //    49,152 B
  float*          stats  = (float*)(ws + 6400000 + 49152);         //       512 B

  float* message = out;  // message accumulates in d_out; final_kernel is in-place

  init_kernel <<<2048, 256, 0, stream>>>(x, Wf, Ws, message, x_bf, B_pack, stats);
  edge_kernel <<<2048, 256, 0, stream>>>(edge_attr, esrc, etgt, x_bf, B_pack, bf, bs, message);
  stats_kernel<<<512, 256, 0, stream>>>(message, stats);
  final_kernel<<<3125, 256, 0, stream>>>(x, stats, gamma, beta, out);
}

// Round 2
// 634.789 us; speedup vs baseline: 1.0988x; 1.0988x over previous
//
#include <hip/hip_runtime.h>
#include <stdint.h>

#define N_NODES 50000
#define N_EDGES 1200000
#define FAN 192       // 2*D + E_DIM
#define NOUT 128      // gate(64) | val(64)
#define ZS 200        // LDS row stride for Z tile (bf16 elems), padded
#define TILE_E 64
#define N_TILES (N_EDGES / TILE_E)   // 18750
#define BN_EPS 1e-5f
#define LOG2E 1.44269504088896340736f
#define LN2   0.69314718055994530942f

typedef __bf16 bf16x8 __attribute__((ext_vector_type(8)));
typedef float  f32x4  __attribute__((ext_vector_type(4)));

__device__ __forceinline__ unsigned short f2bf(float f) {
  unsigned int b = __float_as_uint(f);
  b += 0x7fff + ((b >> 16) & 1);          // RNE
  return (unsigned short)(b >> 16);
}

// fast activations on the transcendental pipe (v_exp_f32 / v_log_f32 / v_rcp_f32)
__device__ __forceinline__ float fast_sigmoid(float x) {
  return __builtin_amdgcn_rcpf(1.f + __builtin_amdgcn_exp2f(-LOG2E * x));
}
__device__ __forceinline__ float fast_softplus(float x) {
  float t = __builtin_amdgcn_exp2f(-LOG2E * fabsf(x));
  return fmaxf(x, 0.f) + LN2 * __builtin_amdgcn_logf(1.f + t);
}
__device__ __forceinline__ float softplus_precise(float x) {
  return fmaxf(x, 0.f) + log1pf(__expf(-fabsf(x)));   // only used in tiny final kernel
}

// raw barrier: LDS ordering only — does NOT drain vmcnt, so atomics stay in flight
__device__ __forceinline__ void lds_barrier() {
  asm volatile("s_waitcnt lgkmcnt(0)" ::: "memory");
  __builtin_amdgcn_sched_barrier(0);
  __builtin_amdgcn_s_barrier();
  __builtin_amdgcn_sched_barrier(0);
}

// ---------------- Kernel A: init / pack ----------------
__global__ void init_kernel(const float* __restrict__ x,
                            const float* __restrict__ Wf,
                            const float* __restrict__ Ws,
                            float* __restrict__ message,
                            unsigned short* __restrict__ x_bf,
                            unsigned short* __restrict__ B_pack,
                            float* __restrict__ stats) {
  const int T0 = 800000;            // zero message, uint4 granularity
  const int T1 = T0 + 800000;       // x f32 -> bf16, float4 granularity
  const int T2 = T1 + NOUT * FAN;   // pack B
  const int T3 = T2 + 128;          // zero stats
  for (int id = blockIdx.x * 256 + threadIdx.x; id < T3; id += gridDim.x * 256) {
    if (id < T0) {
      ((uint4*)message)[id] = make_uint4(0u, 0u, 0u, 0u);
    } else if (id < T1) {
      int i = id - T0;
      float4 v = ((const float4*)x)[i];
      unsigned int lo = (unsigned int)f2bf(v.x) | ((unsigned int)f2bf(v.y) << 16);
      unsigned int hi = (unsigned int)f2bf(v.z) | ((unsigned int)f2bf(v.w) << 16);
      ((uint2*)x_bf)[i] = make_uint2(lo, hi);
    } else if (id < T2) {
      int p = id - T1;
      int n = p / FAN, k = p - n * FAN;
      float v = (n < 64) ? Wf[n * FAN + k] : Ws[(n - 64) * FAN + k];
      B_pack[n * FAN + k] = f2bf(v);
    } else {
      stats[id - T2] = 0.f;
    }
  }
}

// ---------------- Kernel B: edge GEMM + activations + scatter ----------------
__global__ __launch_bounds__(256)
void edge_kernel(const float* __restrict__ edge_attr,
                 const int* __restrict__ edge_source,
                 const int* __restrict__ edge_target,
                 const unsigned short* __restrict__ x_bf,
                 const unsigned short* __restrict__ B_pack,
                 const float* __restrict__ bf_bias,
                 const float* __restrict__ bs_bias,
                 float* __restrict__ message) {
  __shared__ unsigned short Zt[TILE_E * ZS];
  __shared__ int lds_src[TILE_E];

  const int t  = threadIdx.x;
  const int w  = t >> 6;       // wave 0..3
  const int l  = t & 63;       // lane
  const int ln = l & 15;       // MFMA col/row-in-16
  const int lk = l >> 4;       // k-chunk 0..3

  // B fragments in registers: wave w owns gate cols [16w,16w+16) and val cols
  // [64+16w, 64+16w+16)  (2 n-tiles x 6 k-steps x 8 bf16 = 48 VGPRs)
  bf16x8 bfrag[2][6];
  #pragma unroll
  for (int g = 0; g < 2; ++g) {
    int n = (w + 4 * g) * 16 + ln;
    #pragma unroll
    for (int kk = 0; kk < 6; ++kk)
      bfrag[g][kk] = *(const bf16x8*)(B_pack + n * FAN + kk * 32 + lk * 8);
  }
  const float bfv = bf_bias[w * 16 + ln];
  const float bsv = bs_bias[w * 16 + ln];

  for (int tile = blockIdx.x; tile < N_TILES; tile += gridDim.x) {
    const int e0 = tile * TILE_E;
    if (t < TILE_E) lds_src[t] = edge_source[e0 + t];

    // stage x[src] | x[tgt] halves: 64 rows x 2 segs x 8 chunks of 16B
    #pragma unroll
    for (int it = 0; it < 4; ++it) {
      int c = t + it * 256;             // [0,1024)
      int row = c >> 4, sub = c & 15;
      int seg = sub >> 3, j = sub & 7;
      int node = seg ? edge_target[e0 + row] : edge_source[e0 + row];
      uint4 v = *(const uint4*)(x_bf + node * 64 + j * 8);
      *(uint4*)(&Zt[row * ZS + seg * 64 + j * 8]) = v;
    }
    // stage edge_attr (contiguous 16KB), convert f32->bf16
    #pragma unroll
    for (int it = 0; it < 4; ++it) {
      int c = t + it * 256;             // [0,1024)
      int row = c >> 4, q = c & 15;
      float4 v = *(const float4*)(edge_attr + (size_t)(e0 + row) * 64 + q * 4);
      unsigned int lo = (unsigned int)f2bf(v.x) | ((unsigned int)f2bf(v.y) << 16);
      unsigned int hi = (unsigned int)f2bf(v.z) | ((unsigned int)f2bf(v.w) << 16);
      *(uint2*)(&Zt[row * ZS + 128 + q * 4]) = make_uint2(lo, hi);
    }
    lds_barrier();

    // GEMM: [64 edges x 192] @ [192 x 128] ; wave w does all 4 m-tiles for its 2 n-tiles
    f32x4 acc[4][2] = {};
    #pragma unroll
    for (int kk = 0; kk < 6; ++kk) {
      #pragma unroll
      for (int i = 0; i < 4; ++i) {
        bf16x8 a = *(const bf16x8*)(&Zt[(i * 16 + ln) * ZS + kk * 32 + lk * 8]);
        acc[i][0] = __builtin_amdgcn_mfma_f32_16x16x32_bf16(a, bfrag[0][kk], acc[i][0], 0, 0, 0);
        acc[i][1] = __builtin_amdgcn_mfma_f32_16x16x32_bf16(a, bfrag[1][kk], acc[i][1], 0, 0, 0);
      }
    }

    // epilogue: activations + scatter  (C/D layout: col=ln, row=(lk*4+r))
    #pragma unroll
    for (int i = 0; i < 4; ++i) {
      #pragma unroll
      for (int r = 0; r < 4; ++r) {
        float gl = acc[i][0][r] + bfv;
        float vl = acc[i][1][r] + bsv;
        float gate = fast_sigmoid(gl);
        float val  = fast_softplus(vl);
        int m = i * 16 + lk * 4 + r;
        atomicAdd(&message[(size_t)lds_src[m] * 64 + w * 16 + ln], gate * val);
      }
    }
    lds_barrier();   // Zt reuse by next tile (no vmcnt drain: atomics keep flowing)
  }
}

// ---------------- Kernel C: BN stats (sum, sumsq per channel) ----------------
__global__ void stats_kernel(const float* __restrict__ msg,
                             float* __restrict__ stats) {
  __shared__ float red[256];
  int t = threadIdx.x;
  int c = t & 63, g = t >> 6;
  float s1 = 0.f, s2 = 0.f;
  for (int r = blockIdx.x * 4 + g; r < N_NODES; r += gridDim.x * 4) {
    float v = msg[(size_t)r * 64 + c];
    s1 += v; s2 += v * v;
  }
  red[t] = s1;
  __syncthreads();
  if (t < 64) atomicAdd(&stats[t], red[t] + red[t + 64] + red[t + 128] + red[t + 192]);
  __syncthreads();
  red[t] = s2;
  __syncthreads();
  if (t < 64) atomicAdd(&stats[64 + t], red[t] + red[t + 64] + red[t + 128] + red[t + 192]);
}

// ---------------- Kernel D: BN apply + residual softplus (in-place on out) ----------------
__global__ void final_kernel(const float* __restrict__ x,
                             const float* __restrict__ stats,
                             const float* __restrict__ gamma,
                             const float* __restrict__ beta,
                             float* __restrict__ out) {
  int idx = blockIdx.x * 256 + threadIdx.x;
  if (idx >= 800000) return;
  float4 mv = ((const float4*)out)[idx];
  float4 xv = ((const float4*)x)[idx];
  int c0 = (idx & 15) * 4;
  float m[4]  = {mv.x, mv.y, mv.z, mv.w};
  float xx[4] = {xv.x, xv.y, xv.z, xv.w};
  float r[4];
  #pragma unroll
  for (int j = 0; j < 4; ++j) {
    int c = c0 + j;
    float mean = stats[c] * (1.f / N_NODES);
    float var  = stats[64 + c] * (1.f / N_NODES) - mean * mean;
    float bn = (m[j] - mean) * rsqrtf(var + BN_EPS) * gamma[c] + beta[c];
    r[j] = softplus_precise(xx[j] + bn);
  }
  ((float4*)out)[idx] = make_float4(r[0], r[1], r[2], r[3]);
}

extern "C" void kernel_launch(void* const* d_in, const int* in_sizes, int n_in,
                              void* d_out, int out_size, void* d_ws, size_t ws_size,
                              hipStream_t stream) {
  const float* x         = (const float*)d_in[0];
  const float* edge_attr = (const float*)d_in[1];
  const float* Wf        = (const float*)d_in[2];
  const float* bf        = (const float*)d_in[3];
  const float* Ws        = (const float*)d_in[4];
  const float* bs        = (const float*)d_in[5];
  const float* gamma     = (const float*)d_in[6];
  const float* beta      = (const float*)d_in[7];
  const int*   esrc      = (const int*)d_in[8];
  const int*   etgt      = (const int*)d_in[9];
  float* out = (float*)d_out;

  uint8_t* ws = (uint8_t*)d_ws;
  unsigned short* x_bf   = (unsigned short*)ws;                    // 6,400,000 B
  unsigned short* B_pack = (unsigned short*)(ws + 6400000);        //    49,152 B
  float*          stats  = (float*)(ws + 6400000 + 49152);         //       512 B

  float* message = out;  // message accumulates in d_out; final_kernel is in-place

  init_kernel <<<2048, 256, 0, stream>>>(x, Wf, Ws, message, x_bf, B_pack, stats);
  edge_kernel <<<3125, 256, 0, stream>>>(edge_attr, esrc, etgt, x_bf, B_pack, bf, bs, message);
  stats_kernel<<<512, 256, 0, stream>>>(message, stats);
  final_kernel<<<3125, 256, 0, stream>>>(x, stats, gamma, beta, out);
}